// Round 1
// baseline (170.336 us; speedup 1.0000x reference)
//
#include <hip/hip_runtime.h>
#include <math.h>

#define V  50257
#define H  1032
#define INW 2064
#define S  8192

// d_out flat layout (fp32): [output V][attn_context H][hidden H][attn_w S]
#define O_CTX  50257
#define O_HID  51289
#define O_ATTN 52321

__device__ __forceinline__ float waveReduceSum(float v) {
#pragma unroll
  for (int off = 32; off > 0; off >>= 1) v += __shfl_down(v, off);
  return v;
}

// K1: GRU cell. 258 blocks x 256 threads; wave w of block b owns gate-row j = b*4+w.
// Computes h_new[j] = (1-z)*n + z*h. Also zeroes the v accumulator (block 0).
__global__ __launch_bounds__(256) void gru_kernel(
    const int* __restrict__ word, const float* __restrict__ emb,
    const float* __restrict__ lc, const float* __restrict__ ph,
    const float* __restrict__ W_ih, const float* __restrict__ W_hh,
    const float* __restrict__ b_ih, const float* __restrict__ b_hh,
    float* __restrict__ hnew, float* __restrict__ hid_out,
    float* __restrict__ v_acc) {
  int t = threadIdx.x, wave = t >> 6, lane = t & 63;
  if (blockIdx.x == 0) {
    for (int k = t; k < H; k += 256) v_acc[k] = 0.f;
  }
  int j = blockIdx.x * 4 + wave;  // 0..1031

  const float4* erow = (const float4*)(emb + (size_t)word[0] * H);
  const float4* lc4  = (const float4*)lc;
  const float4* ph4  = (const float4*)ph;

  const float4* wr = (const float4*)(W_ih + (size_t)j * INW);
  const float4* wz = (const float4*)(W_ih + (size_t)(H + j) * INW);
  const float4* wn = (const float4*)(W_ih + (size_t)(2 * H + j) * INW);
  float sir = 0.f, siz = 0.f, sin_ = 0.f;
  for (int i = lane; i < INW / 4; i += 64) {  // 516 float4
    float4 xv = (i < H / 4) ? erow[i] : lc4[i - H / 4];
    float4 a = wr[i]; sir  += xv.x * a.x + xv.y * a.y + xv.z * a.z + xv.w * a.w;
    float4 b = wz[i]; siz  += xv.x * b.x + xv.y * b.y + xv.z * b.z + xv.w * b.w;
    float4 c = wn[i]; sin_ += xv.x * c.x + xv.y * c.y + xv.z * c.z + xv.w * c.w;
  }
  const float4* ur = (const float4*)(W_hh + (size_t)j * H);
  const float4* uz = (const float4*)(W_hh + (size_t)(H + j) * H);
  const float4* un = (const float4*)(W_hh + (size_t)(2 * H + j) * H);
  float shr = 0.f, shz = 0.f, shn = 0.f;
  for (int i = lane; i < H / 4; i += 64) {  // 258 float4
    float4 hv = ph4[i];
    float4 a = ur[i]; shr += hv.x * a.x + hv.y * a.y + hv.z * a.z + hv.w * a.w;
    float4 b = uz[i]; shz += hv.x * b.x + hv.y * b.y + hv.z * b.z + hv.w * b.w;
    float4 c = un[i]; shn += hv.x * c.x + hv.y * c.y + hv.z * c.z + hv.w * c.w;
  }
  sir = waveReduceSum(sir); siz = waveReduceSum(siz); sin_ = waveReduceSum(sin_);
  shr = waveReduceSum(shr); shz = waveReduceSum(shz); shn = waveReduceSum(shn);
  if (lane == 0) {
    float gr = (sir + b_ih[j])         + (shr + b_hh[j]);
    float gz = (siz + b_ih[H + j])     + (shz + b_hh[H + j]);
    float r  = 1.f / (1.f + expf(-gr));
    float z  = 1.f / (1.f + expf(-gz));
    float n  = tanhf((sin_ + b_ih[2 * H + j]) + r * (shn + b_hh[2 * H + j]));
    float hv = (1.f - z) * n + z * ph[j];
    hnew[j] = hv;
    hid_out[j] = hv;
  }
}

// K2: v[k] = sum_j W_a[j][k] * hnew[j].  grid (5, 16): x = 256-col tile, y = 65-row chunk.
__global__ __launch_bounds__(256) void va_kernel(
    const float* __restrict__ W_a, const float* __restrict__ hnew,
    float* __restrict__ v) {
  int k = blockIdx.x * 256 + threadIdx.x;
  if (k >= H) return;
  int j0 = blockIdx.y * 65;
  int j1 = min(j0 + 65, H);
  float acc = 0.f;
  for (int j = j0; j < j1; ++j) acc += W_a[(size_t)j * H + k] * hnew[j];
  atomicAdd(&v[k], acc);
}

// K3: scores[s] = enc[s,:] . v   (b_a . h_new dropped: constant shift cancels in softmax)
__global__ __launch_bounds__(256) void scores_kernel(
    const float* __restrict__ enc, const float* __restrict__ v,
    float* __restrict__ scores) {
  int t = threadIdx.x, wave = t >> 6, lane = t & 63;
  int s = blockIdx.x * 4 + wave;  // 2048 blocks -> 8192 rows
  const float4* row = (const float4*)(enc + (size_t)s * H);
  const float4* v4  = (const float4*)v;
  float acc = 0.f;
  for (int i = lane; i < H / 4; i += 64) {
    float4 a = row[i], b = v4[i];
    acc += a.x * b.x + a.y * b.y + a.z * b.z + a.w * b.w;
  }
  acc = waveReduceSum(acc);
  if (lane == 0) scores[s] = acc;
}

// K4: softmax over 8192 scores -> attn weights (written to d_out). Also zero ctx accum.
__global__ __launch_bounds__(1024) void softmax_kernel(
    const float* __restrict__ scores, float* __restrict__ attn_out,
    float* __restrict__ ctx) {
  __shared__ float sm[1024];
  int t = threadIdx.x;
  float m = -3.4e38f;
  for (int i = t; i < S; i += 1024) m = fmaxf(m, scores[i]);
  sm[t] = m; __syncthreads();
  for (int off = 512; off; off >>= 1) {
    if (t < off) sm[t] = fmaxf(sm[t], sm[t + off]);
    __syncthreads();
  }
  m = sm[0]; __syncthreads();
  float s = 0.f;
  for (int i = t; i < S; i += 1024) s += expf(scores[i] - m);
  sm[t] = s; __syncthreads();
  for (int off = 512; off; off >>= 1) {
    if (t < off) sm[t] += sm[t + off];
    __syncthreads();
  }
  float inv = 1.f / sm[0];
  for (int i = t; i < S; i += 1024) attn_out[i] = expf(scores[i] - m) * inv;
  for (int k = t; k < H; k += 1024) ctx[k] = 0.f;
}

// K5: ctx[k] = sum_s w[s] * enc[s][k].  grid (5, 64): x = col tile, y = 128-row chunk.
__global__ __launch_bounds__(256) void ctx_kernel(
    const float* __restrict__ enc, const float* __restrict__ w,
    float* __restrict__ ctx) {
  int k = blockIdx.x * 256 + threadIdx.x;
  if (k >= H) return;
  int s0 = blockIdx.y * 128;
  float acc = 0.f;
  for (int s = s0; s < s0 + 128; ++s) acc += w[s] * enc[(size_t)s * H + k];
  atomicAdd(&ctx[k], acc);
}

// K6: logits[vi] = [hnew|ctx] . W_out[vi,:] + b_out[vi]  -> d_out[0:V] (raw logits).
// joined vector staged in LDS once per block. Block 0 also emits ctx to d_out.
__global__ __launch_bounds__(256) void logits_kernel(
    const float* __restrict__ hnew, const float* __restrict__ ctx,
    const float* __restrict__ W_out, const float* __restrict__ b_out,
    float* __restrict__ out, float* __restrict__ ctx_out) {
  __shared__ __align__(16) float joined[INW];
  int t = threadIdx.x;
  for (int k = t; k < H; k += 256) {
    joined[k] = hnew[k];
    joined[H + k] = ctx[k];
  }
  if (blockIdx.x == 0) {
    for (int k = t; k < H; k += 256) ctx_out[k] = ctx[k];
  }
  __syncthreads();
  int lane = t & 63;
  int gw = blockIdx.x * 4 + (t >> 6);
  int nw = gridDim.x * 4;
  const float4* j4 = (const float4*)joined;
  for (int vi = gw; vi < V; vi += nw) {
    const float4* row = (const float4*)(W_out + (size_t)vi * INW);
    float acc = 0.f;
    for (int i = lane; i < INW / 4; i += 64) {  // 516 float4
      float4 a = row[i];
      float4 b = j4[i];
      acc += a.x * b.x + a.y * b.y + a.z * b.z + a.w * b.w;
    }
    acc = waveReduceSum(acc);
    if (lane == 0) out[vi] = acc + b_out[vi];
  }
}

// K7: logsumexp over V logits (single block).
__global__ __launch_bounds__(1024) void lse_kernel(
    const float* __restrict__ logits, float* __restrict__ red) {
  __shared__ float sm[1024];
  int t = threadIdx.x;
  float m = -3.4e38f;
  for (int i = t; i < V; i += 1024) m = fmaxf(m, logits[i]);
  sm[t] = m; __syncthreads();
  for (int off = 512; off; off >>= 1) {
    if (t < off) sm[t] = fmaxf(sm[t], sm[t + off]);
    __syncthreads();
  }
  m = sm[0]; __syncthreads();
  float s = 0.f;
  for (int i = t; i < V; i += 1024) s += expf(logits[i] - m);
  sm[t] = s; __syncthreads();
  for (int off = 512; off; off >>= 1) {
    if (t < off) sm[t] += sm[t + off];
    __syncthreads();
  }
  if (t == 0) { red[0] = m; red[1] = logf(sm[0]); }
}

// K8: out = logit - m - log(sum)
__global__ __launch_bounds__(256) void apply_kernel(
    float* __restrict__ out, const float* __restrict__ red) {
  int i = blockIdx.x * 256 + threadIdx.x;
  if (i < V) out[i] = out[i] - red[0] - red[1];
}

extern "C" void kernel_launch(void* const* d_in, const int* in_sizes, int n_in,
                              void* d_out, int out_size, void* d_ws, size_t ws_size,
                              hipStream_t stream) {
  const int*   word  = (const int*)d_in[0];
  const float* lc    = (const float*)d_in[1];
  const float* ph    = (const float*)d_in[2];
  const float* enc   = (const float*)d_in[3];
  const float* emb   = (const float*)d_in[4];
  const float* W_ih  = (const float*)d_in[5];
  const float* W_hh  = (const float*)d_in[6];
  const float* b_ih  = (const float*)d_in[7];
  const float* b_hh  = (const float*)d_in[8];
  const float* W_a   = (const float*)d_in[9];
  // d_in[10] = b_a: unused — adds a constant to all attention scores, cancels in softmax.
  const float* W_out = (const float*)d_in[11];
  const float* b_out = (const float*)d_in[12];
  float* out = (float*)d_out;
  float* ws  = (float*)d_ws;

  // ws layout (floats): hnew[1032] | v[1032] | scores[8192] | ctx[1032] | red[2]
  float* hnew   = ws;
  float* v      = ws + 1032;
  float* scores = ws + 2064;
  float* ctx    = ws + 10256;
  float* red    = ws + 11288;

  gru_kernel<<<258, 256, 0, stream>>>(word, emb, lc, ph, W_ih, W_hh, b_ih, b_hh,
                                      hnew, out + O_HID, v);
  va_kernel<<<dim3(5, 16), 256, 0, stream>>>(W_a, hnew, v);
  scores_kernel<<<2048, 256, 0, stream>>>(enc, v, scores);
  softmax_kernel<<<1, 1024, 0, stream>>>(scores, out + O_ATTN, ctx);
  ctx_kernel<<<dim3(5, 64), 256, 0, stream>>>(enc, out + O_ATTN, ctx);
  logits_kernel<<<2048, 256, 0, stream>>>(hnew, ctx, W_out, b_out, out, out + O_CTX);
  lse_kernel<<<1, 1024, 0, stream>>>(out, red);
  apply_kernel<<<(V + 255) / 256, 256, 0, stream>>>(out, red);
}

// Round 2
// 156.495 us; speedup vs baseline: 1.0884x; 1.0884x over previous
//
#include <hip/hip_runtime.h>
#include <math.h>

#define V  50257
#define H  1032
#define INW 2064
#define S  8192

// d_out flat layout (fp32): [output V][attn_context H][hidden H][attn_w S]
#define O_CTX  50257
#define O_HID  51289
#define O_ATTN 52321

#define NPART 2048   // logits partial-lse pairs

__device__ __forceinline__ float waveReduceSum(float v) {
#pragma unroll
  for (int off = 32; off > 0; off >>= 1) v += __shfl_down(v, off);
  return v;
}

// K1: GRU cell. 258 blocks x 256 threads; wave w of block b owns gate-row j = b*4+w.
// Also zeroes the v accumulator (block 0).
__global__ __launch_bounds__(256) void gru_kernel(
    const int* __restrict__ word, const float* __restrict__ emb,
    const float* __restrict__ lc, const float* __restrict__ ph,
    const float* __restrict__ W_ih, const float* __restrict__ W_hh,
    const float* __restrict__ b_ih, const float* __restrict__ b_hh,
    float* __restrict__ hnew, float* __restrict__ hid_out,
    float* __restrict__ v_acc) {
  int t = threadIdx.x, wave = t >> 6, lane = t & 63;
  if (blockIdx.x == 0) {
    for (int k = t; k < H; k += 256) v_acc[k] = 0.f;
  }
  int j = blockIdx.x * 4 + wave;  // 0..1031

  const float4* erow = (const float4*)(emb + (size_t)word[0] * H);
  const float4* lc4  = (const float4*)lc;
  const float4* ph4  = (const float4*)ph;

  const float4* wr = (const float4*)(W_ih + (size_t)j * INW);
  const float4* wz = (const float4*)(W_ih + (size_t)(H + j) * INW);
  const float4* wn = (const float4*)(W_ih + (size_t)(2 * H + j) * INW);
  float sir = 0.f, siz = 0.f, sin_ = 0.f;
  for (int i = lane; i < INW / 4; i += 64) {  // 516 float4
    float4 xv = (i < H / 4) ? erow[i] : lc4[i - H / 4];
    float4 a = wr[i]; sir  += xv.x * a.x + xv.y * a.y + xv.z * a.z + xv.w * a.w;
    float4 b = wz[i]; siz  += xv.x * b.x + xv.y * b.y + xv.z * b.z + xv.w * b.w;
    float4 c = wn[i]; sin_ += xv.x * c.x + xv.y * c.y + xv.z * c.z + xv.w * c.w;
  }
  const float4* ur = (const float4*)(W_hh + (size_t)j * H);
  const float4* uz = (const float4*)(W_hh + (size_t)(H + j) * H);
  const float4* un = (const float4*)(W_hh + (size_t)(2 * H + j) * H);
  float shr = 0.f, shz = 0.f, shn = 0.f;
  for (int i = lane; i < H / 4; i += 64) {  // 258 float4
    float4 hv = ph4[i];
    float4 a = ur[i]; shr += hv.x * a.x + hv.y * a.y + hv.z * a.z + hv.w * a.w;
    float4 b = uz[i]; shz += hv.x * b.x + hv.y * b.y + hv.z * b.z + hv.w * b.w;
    float4 c = un[i]; shn += hv.x * c.x + hv.y * c.y + hv.z * c.z + hv.w * c.w;
  }
  sir = waveReduceSum(sir); siz = waveReduceSum(siz); sin_ = waveReduceSum(sin_);
  shr = waveReduceSum(shr); shz = waveReduceSum(shz); shn = waveReduceSum(shn);
  if (lane == 0) {
    float gr = (sir + b_ih[j])         + (shr + b_hh[j]);
    float gz = (siz + b_ih[H + j])     + (shz + b_hh[H + j]);
    float r  = 1.f / (1.f + expf(-gr));
    float z  = 1.f / (1.f + expf(-gz));
    float n  = tanhf((sin_ + b_ih[2 * H + j]) + r * (shn + b_hh[2 * H + j]));
    float hv = (1.f - z) * n + z * ph[j];
    hnew[j] = hv;
    hid_out[j] = hv;
  }
}

// K2: v[k] = sum_j W_a[j][k] * hnew[j].  grid (5, 16). Also zeroes ctx (y==0 row).
__global__ __launch_bounds__(256) void va_kernel(
    const float* __restrict__ W_a, const float* __restrict__ hnew,
    float* __restrict__ v, float* __restrict__ ctx) {
  int k = blockIdx.x * 256 + threadIdx.x;
  if (k >= H) return;
  if (blockIdx.y == 0) ctx[k] = 0.f;
  int j0 = blockIdx.y * 65;
  int j1 = min(j0 + 65, H);
  float acc = 0.f;
  for (int j = j0; j < j1; ++j) acc += W_a[(size_t)j * H + k] * hnew[j];
  atomicAdd(&v[k], acc);
}

// K3: scores[s] = enc[s,:] . v   (b_a . h_new dropped: constant shift cancels in softmax)
__global__ __launch_bounds__(256) void scores_kernel(
    const float* __restrict__ enc, const float* __restrict__ v,
    float* __restrict__ scores) {
  int t = threadIdx.x, wave = t >> 6, lane = t & 63;
  int s = blockIdx.x * 4 + wave;  // 2048 blocks -> 8192 rows
  const float4* row = (const float4*)(enc + (size_t)s * H);
  const float4* v4  = (const float4*)v;
  float acc = 0.f;
  for (int i = lane; i < H / 4; i += 64) {
    float4 a = row[i], b = v4[i];
    acc += a.x * b.x + a.y * b.y + a.z * b.z + a.w * b.w;
  }
  acc = waveReduceSum(acc);
  if (lane == 0) scores[s] = acc;
}

// K4: ctx[k] = sum_s w[s]*enc[s][k] with softmax recomputed per block (deterministic,
// all from L2). grid (5, 128): x = 256-col tile, y = 64-row chunk.
// Col-tile 0 also writes attn weights to d_out.
__global__ __launch_bounds__(256) void ctx_kernel(
    const float* __restrict__ enc, const float* __restrict__ scores,
    float* __restrict__ ctx, float* __restrict__ attn_out) {
  __shared__ float red[256];
  __shared__ float wsh[64];
  int t = threadIdx.x;
  float m = -3.4e38f;
  for (int i = t; i < S; i += 256) m = fmaxf(m, scores[i]);
  red[t] = m; __syncthreads();
  for (int off = 128; off; off >>= 1) {
    if (t < off) red[t] = fmaxf(red[t], red[t + off]);
    __syncthreads();
  }
  m = red[0]; __syncthreads();
  float s = 0.f;
  for (int i = t; i < S; i += 256) s += expf(scores[i] - m);
  red[t] = s; __syncthreads();
  for (int off = 128; off; off >>= 1) {
    if (t < off) red[t] += red[t + off];
    __syncthreads();
  }
  float inv = 1.f / red[0];
  int s0 = blockIdx.y * 64;
  if (t < 64) wsh[t] = expf(scores[s0 + t] - m) * inv;
  __syncthreads();
  if (blockIdx.x == 0 && t < 64) attn_out[s0 + t] = wsh[t];
  int k = blockIdx.x * 256 + t;
  if (k < H) {
    float acc = 0.f;
    for (int si = 0; si < 64; ++si) acc += wsh[si] * enc[(size_t)(s0 + si) * H + k];
    atomicAdd(&ctx[k], acc);
  }
}

// K5: logits[vi] = [hnew|ctx] . W_out[vi,:] + b_out[vi]  -> d_out[0:V] (raw logits)
// + per-block online logsumexp partial (m_b, s_b) -> partials[2*blk].
// Block 0 also emits ctx to d_out.
__global__ __launch_bounds__(256) void logits_kernel(
    const float* __restrict__ hnew, const float* __restrict__ ctx,
    const float* __restrict__ W_out, const float* __restrict__ b_out,
    float* __restrict__ out, float* __restrict__ ctx_out,
    float* __restrict__ partials) {
  __shared__ __align__(16) float joined[INW];
  __shared__ float wm[4], wsv[4];
  int t = threadIdx.x;
  for (int k = t; k < H; k += 256) {
    joined[k] = hnew[k];
    joined[H + k] = ctx[k];
  }
  if (blockIdx.x == 0) {
    for (int k = t; k < H; k += 256) ctx_out[k] = ctx[k];
  }
  __syncthreads();
  int lane = t & 63, wv = t >> 6;
  int gw = blockIdx.x * 4 + wv;
  const float4* j4 = (const float4*)joined;
  float lm = -3.4e38f, ls = 0.f;
  for (int vi = gw; vi < V; vi += NPART * 4) {
    const float4* row = (const float4*)(W_out + (size_t)vi * INW);
    float acc = 0.f;
    for (int i = lane; i < INW / 4; i += 64) {  // 516 float4
      float4 a = row[i];
      float4 b = j4[i];
      acc += a.x * b.x + a.y * b.y + a.z * b.z + a.w * b.w;
    }
    acc = waveReduceSum(acc);
    if (lane == 0) {
      float x = acc + b_out[vi];
      out[vi] = x;
      float nm = fmaxf(lm, x);
      ls = ls * expf(lm - nm) + expf(x - nm);
      lm = nm;
    }
  }
  if (lane == 0) { wm[wv] = lm; wsv[wv] = ls; }
  __syncthreads();
  if (t == 0) {
    float m = wm[0], sb = wsv[0];
    for (int i = 1; i < 4; ++i) {
      float nm = fmaxf(m, wm[i]);
      sb = sb * expf(m - nm) + wsv[i] * expf(wm[i] - nm);
      m = nm;
    }
    partials[2 * blockIdx.x]     = m;
    partials[2 * blockIdx.x + 1] = sb;
  }
}

// K6: combine 2048 partials (redundantly per block, deterministic) and apply
// out[i] = logit - lse.
__global__ __launch_bounds__(256) void apply_kernel(
    float* __restrict__ out, const float* __restrict__ partials) {
  __shared__ float mm[256], ssv[256];
  int t = threadIdx.x;
  float m = -3.4e38f, s = 0.f;
  for (int i = t; i < NPART; i += 256) {
    float bm = partials[2 * i], bs = partials[2 * i + 1];
    float nm = fmaxf(m, bm);
    s = s * expf(m - nm) + bs * expf(bm - nm);
    m = nm;
  }
  mm[t] = m; ssv[t] = s; __syncthreads();
  for (int off = 128; off; off >>= 1) {
    if (t < off) {
      float m2 = mm[t + off], s2 = ssv[t + off];
      float nm = fmaxf(mm[t], m2);
      ssv[t] = ssv[t] * expf(mm[t] - nm) + s2 * expf(m2 - nm);
      mm[t] = nm;
    }
    __syncthreads();
  }
  float L = mm[0] + logf(ssv[0]);
  int i = blockIdx.x * 256 + t;
  if (i < V) out[i] -= L;
}

extern "C" void kernel_launch(void* const* d_in, const int* in_sizes, int n_in,
                              void* d_out, int out_size, void* d_ws, size_t ws_size,
                              hipStream_t stream) {
  const int*   word  = (const int*)d_in[0];
  const float* lc    = (const float*)d_in[1];
  const float* ph    = (const float*)d_in[2];
  const float* enc   = (const float*)d_in[3];
  const float* emb   = (const float*)d_in[4];
  const float* W_ih  = (const float*)d_in[5];
  const float* W_hh  = (const float*)d_in[6];
  const float* b_ih  = (const float*)d_in[7];
  const float* b_hh  = (const float*)d_in[8];
  const float* W_a   = (const float*)d_in[9];
  // d_in[10] = b_a: unused — constant shift of all attention scores, cancels in softmax.
  const float* W_out = (const float*)d_in[11];
  const float* b_out = (const float*)d_in[12];
  float* out = (float*)d_out;
  float* ws  = (float*)d_ws;

  // ws layout (floats): hnew[1032] | v[1032] | scores[8192] | ctx[1032] | partials[4096]
  float* hnew     = ws;
  float* v        = ws + 1032;
  float* scores   = ws + 2064;
  float* ctx      = ws + 10256;
  float* partials = ws + 11288;

  gru_kernel<<<258, 256, 0, stream>>>(word, emb, lc, ph, W_ih, W_hh, b_ih, b_hh,
                                      hnew, out + O_HID, v);
  va_kernel<<<dim3(5, 16), 256, 0, stream>>>(W_a, hnew, v, ctx);
  scores_kernel<<<2048, 256, 0, stream>>>(enc, v, scores);
  ctx_kernel<<<dim3(5, 128), 256, 0, stream>>>(enc, scores, ctx, out + O_ATTN);
  logits_kernel<<<NPART, 256, 0, stream>>>(hnew, ctx, W_out, b_out, out,
                                           out + O_CTX, partials);
  apply_kernel<<<(V + 255) / 256, 256, 0, stream>>>(out, partials);
}